// Round 3
// baseline (123.329 us; speedup 1.0000x reference)
//
#include <hip/hip_runtime.h>
#include <math.h>

// Problem constants: B=4, N=256, C=512, H=8, Dh=64
#define BB 4
#define NN 256
#define CC 512
#define HH 8
#define DH 64

typedef __attribute__((ext_vector_type(8))) short bf16x8;
typedef __attribute__((ext_vector_type(4))) float f32x4;
typedef __attribute__((ext_vector_type(2))) float f32x2;

__device__ inline unsigned short f2bf(float f) {
  unsigned u = __float_as_uint(f);
  u += 0x7FFFu + ((u >> 16) & 1u);  // round-to-nearest-even
  return (unsigned short)(u >> 16);
}
__device__ inline float bf2f(unsigned short s) {
  return __uint_as_float((unsigned)s << 16);
}

// ---------------------------------------------------------------------------
// Fused fp32 -> (hi, lo) bf16 split for all three inputs in ONE launch.
// Segments (blocks): x = 512, w_qkv = 768, w_proj = 256  -> grid 1536.
// ---------------------------------------------------------------------------
__global__ __launch_bounds__(256) void cvt_hilo3(
    const float* __restrict__ in0, unsigned short* __restrict__ h0,
    unsigned short* __restrict__ l0, const float* __restrict__ in1,
    unsigned short* __restrict__ h1, unsigned short* __restrict__ l1,
    const float* __restrict__ in2, unsigned short* __restrict__ h2,
    unsigned short* __restrict__ l2) {
  int b = blockIdx.x;
  const float* in;
  unsigned short *h, *l;
  if (b < 512) {
    in = in0; h = h0; l = l0;
  } else if (b < 1280) {
    in = in1; h = h1; l = l1; b -= 512;
  } else {
    in = in2; h = h2; l = l2; b -= 1280;
  }
  int i = (b * 256 + threadIdx.x) * 4;
  float4 f = *(const float4*)(in + i);
  float fa[4] = {f.x, f.y, f.z, f.w};
  ushort4 hv, lv;
  unsigned short* hp = (unsigned short*)&hv;
  unsigned short* lp = (unsigned short*)&lv;
#pragma unroll
  for (int j = 0; j < 4; j++) {
    unsigned short hb = f2bf(fa[j]);
    hp[j] = hb;
    lp[j] = f2bf(fa[j] - bf2f(hb));
  }
  *(ushort4*)(h + i) = hv;
  *(ushort4*)(l + i) = lv;
}

// ---------------------------------------------------------------------------
// MFMA GEMM, bf16 hi/lo split (3 products): C = A * B^T (+bias).
// LDS double-buffer with ONE barrier per K-step. Per iter: compute buf[p]
// || store buf[p^1] from prefetch regs || issue global loads k+128 -> barrier.
// 256 thr = 4 waves; tile 64x64; wave -> 32x32 (2x2 mfma 16x16x32). BK=64.
// LDS rows padded to 72 shorts (144B): b128 frags conflict-free.
// LDS = 72KB -> 2 blocks/CU. M,N multiples of 64; K mult of 64.
// ---------------------------------------------------------------------------
template <bool BIAS>
__global__ __launch_bounds__(256, 2) void gemm_mfma(
    const unsigned short* __restrict__ Ah, const unsigned short* __restrict__ Al,
    const unsigned short* __restrict__ Bh, const unsigned short* __restrict__ Bl,
    const float* __restrict__ bias, float* __restrict__ C, int M, int N,
    int K) {
  __shared__ unsigned short sAh[2][64][72], sAl[2][64][72];
  __shared__ unsigned short sBh[2][64][72], sBl[2][64][72];
  const int t = threadIdx.x;
  const int lane = t & 63;
  const int w = t >> 6;
  const int bm = blockIdx.y * 64;
  const int bn = blockIdx.x * 64;
  const int wr = (w >> 1) * 32;  // wave row offset in tile
  const int wc = (w & 1) * 32;   // wave col offset
  const int quad = lane >> 4;
  const int l16 = lane & 15;

  // staging: 512 slots of 8 shorts per array
  const int r0 = t >> 3;       // 0..31
  const int r1 = r0 + 32;      // 32..63
  const int c8 = (t & 7) * 8;  // 0..56

  const size_t a0 = (size_t)(bm + r0) * K + c8;
  const size_t a1 = (size_t)(bm + r1) * K + c8;
  const size_t b0 = (size_t)(bn + r0) * K + c8;
  const size_t b1 = (size_t)(bn + r1) * K + c8;

  f32x4 acc[2][2];
#pragma unroll
  for (int i = 0; i < 2; i++)
#pragma unroll
    for (int j = 0; j < 2; j++) {
      acc[i][j][0] = 0.f;
      acc[i][j][1] = 0.f;
      acc[i][j][2] = 0.f;
      acc[i][j][3] = 0.f;
    }

  uint4 pa0, pa1, pa2, pa3, pb0, pb1, pb2, pb3;
#define GLOADS(K0)                       \
  pa0 = *(const uint4*)(Ah + a0 + (K0)); \
  pa1 = *(const uint4*)(Ah + a1 + (K0)); \
  pa2 = *(const uint4*)(Al + a0 + (K0)); \
  pa3 = *(const uint4*)(Al + a1 + (K0)); \
  pb0 = *(const uint4*)(Bh + b0 + (K0)); \
  pb1 = *(const uint4*)(Bh + b1 + (K0)); \
  pb2 = *(const uint4*)(Bl + b0 + (K0)); \
  pb3 = *(const uint4*)(Bl + b1 + (K0));

#define STORE(P)                  \
  *(uint4*)&sAh[P][r0][c8] = pa0; \
  *(uint4*)&sAh[P][r1][c8] = pa1; \
  *(uint4*)&sAl[P][r0][c8] = pa2; \
  *(uint4*)&sAl[P][r1][c8] = pa3; \
  *(uint4*)&sBh[P][r0][c8] = pb0; \
  *(uint4*)&sBh[P][r1][c8] = pb1; \
  *(uint4*)&sBl[P][r0][c8] = pb2; \
  *(uint4*)&sBl[P][r1][c8] = pb3;

  GLOADS(0)
  STORE(0)
  __syncthreads();
  GLOADS(64)

  int p = 0;
  for (int k0 = 0; k0 < K; k0 += 64) {
#pragma unroll
    for (int kk = 0; kk < 2; kk++) {
      const int kc = kk * 32 + quad * 8;
      bf16x8 ah[2], al[2], bh[2], bl[2];
#pragma unroll
      for (int i = 0; i < 2; i++) {
        ah[i] = *(const bf16x8*)&sAh[p][wr + i * 16 + l16][kc];
        al[i] = *(const bf16x8*)&sAl[p][wr + i * 16 + l16][kc];
        bh[i] = *(const bf16x8*)&sBh[p][wc + i * 16 + l16][kc];
        bl[i] = *(const bf16x8*)&sBl[p][wc + i * 16 + l16][kc];
      }
#pragma unroll
      for (int i = 0; i < 2; i++)
#pragma unroll
        for (int j = 0; j < 2; j++) {
          acc[i][j] = __builtin_amdgcn_mfma_f32_16x16x32_bf16(
              ah[i], bh[j], acc[i][j], 0, 0, 0);
          acc[i][j] = __builtin_amdgcn_mfma_f32_16x16x32_bf16(
              ah[i], bl[j], acc[i][j], 0, 0, 0);
          acc[i][j] = __builtin_amdgcn_mfma_f32_16x16x32_bf16(
              al[i], bh[j], acc[i][j], 0, 0, 0);
        }
    }
    if (k0 + 64 < K) {
      STORE(p ^ 1)
      if (k0 + 128 < K) {
        GLOADS(k0 + 128)
      }
    }
    __syncthreads();
    p ^= 1;
  }
#undef GLOADS
#undef STORE

  // epilogue: C/D layout col=lane&15, row=quad*4+reg (verified m89/m91)
#pragma unroll
  for (int i = 0; i < 2; i++)
#pragma unroll
    for (int j = 0; j < 2; j++) {
      int n = bn + wc + j * 16 + l16;
      float bv = BIAS ? bias[n] : 0.f;
#pragma unroll
      for (int r = 0; r < 4; r++) {
        int m = bm + wr + i * 16 + quad * 4 + r;
        C[(size_t)m * N + n] = acc[i][j][r] + bv;
      }
    }
}

// ---------------------------------------------------------------------------
// Fused Fourier attention v4.1. Grid (16,H,B); 512 thr = 8 waves, 2 q/wave.
//  - AV phase via MFMA on hi/lo bf16 P tile (wave role: dim-chunk nc=wv&3,
//    key-half g2=wv>>2); cross-wave pair-sum at end.
//  - Score in packed f32x2.
//  - FIX vs v4 (NaN): diff MUST be (q - k) + 1e-30 in THAT order. The v4
//    form q + (1e-30 - k) rounds the eps away, and a bit-exact q_d == k_d
//    collision (expected ~3 per run) gives d=0 -> 0/0 = NaN.
// Barriers: B1 (stage safe) / B2 (staged ready) / B3 (P ready).
// ---------------------------------------------------------------------------
__global__ __launch_bounds__(512, 4) void fourier_attn(
    const float* __restrict__ qkv, const float* __restrict__ paramR,
    unsigned short* __restrict__ aoh, unsigned short* __restrict__ aol) {
  __shared__ float Kt[64][68];            // K tile, row-major, padded
  __shared__ float Vs[64][68];            // V tile, row-major, padded
  __shared__ float Qs[16][64];            // staged queries (broadcast reads)
  __shared__ unsigned short Pah[16][72];  // a4 hi (bf16), padded 144B rows
  __shared__ unsigned short Pal[16][72];  // a4 lo
  __shared__ float Sden[16];              // per-query denominators
  __shared__ f32x4 Red[4][64];            // cross-wave partial sums

  const int t = threadIdx.x;
  const int lane = t & 63;
  const int wv = t >> 6;  // 0..7
  const int quad = lane >> 4;
  const int l16 = lane & 15;
  const int qc = blockIdx.x;
  const int h = blockIdx.y;
  const int b = blockIdx.z;
  const float R = paramR[0];
  const float cR = R * 0.15915494309189535f;  // R / (2*pi)

  const float* base = qkv + (size_t)b * NN * (3 * CC) + h * DH;

  if (t < 256) {
    int r = t >> 4;
    int c4 = (t & 15) << 2;
    *(float4*)&Qs[r][c4] =
        *(const float4*)(base + (size_t)(qc * 16 + r) * (3 * CC) + c4);
  }

  const int qi0 = wv * 2, qi1 = wv * 2 + 1;
  float Sp[2] = {0.f, 0.f};
  f32x4 oacc;
  oacc[0] = 0.f; oacc[1] = 0.f; oacc[2] = 0.f; oacc[3] = 0.f;

  // AV-phase role of this wave: dims chunk nc, key-half g2
  const int nc = wv & 3;
  const int g2 = wv >> 2;
  const int kb = g2 * 32 + quad * 8;

  // prefetch registers for one K/V tile (2 float4 each)
  float4 pk[2], pv[2];
#define LOADT(JT)                                                   \
  _Pragma("unroll") for (int u0 = 0; u0 < 2; u0++) {                \
    int u = t + 512 * u0;                                           \
    int r_ = u >> 4;                                                \
    int c4_ = (u & 15) << 2;                                        \
    const float* row_ = base + (size_t)((JT) * 64 + r_) * (3 * CC); \
    pk[u0] = *(const float4*)(row_ + CC + c4_);                     \
    pv[u0] = *(const float4*)(row_ + 2 * CC + c4_);                 \
  }

  LOADT(0)

  const f32x2 eps2 = {1e-30f, 1e-30f};
  const f32x2 cR2 = {cR, cR};

  for (int jt = 0; jt < 4; jt++) {
    __syncthreads();  // B1: prev tile's AV reads of Vs/Pah done
#pragma unroll
    for (int u0 = 0; u0 < 2; u0++) {
      int u = t + 512 * u0;
      int r = u >> 4;          // key row
      int c4 = (u & 15) << 2;  // dim
      *(float4*)&Kt[r][c4] = pk[u0];
      *(float4*)&Vs[r][c4] = pv[u0];
    }
    __syncthreads();  // B2: staged tile (and Qs on jt=0) ready
    if (jt < 3) {
      LOADT(jt + 1)  // in flight across score+AV below
    }

    // ---- score phase: lane = key, packed f32x2 math
    f32x2 nmA0 = {1.f, 1.f}, nmB0 = {1.f, 1.f};
    f32x2 nmA1 = {1.f, 1.f}, nmB1 = {1.f, 1.f};
    f32x2 dnA0 = {1.f, 1.f}, dnB0 = {1.f, 1.f};
    f32x2 dnA1 = {1.f, 1.f}, dnB1 = {1.f, 1.f};
#pragma unroll
    for (int d4 = 0; d4 < 16; d4++) {
      float4 k4 = *(const float4*)&Kt[lane][4 * d4];
      float4 qa = *(const float4*)&Qs[qi0][4 * d4];
      float4 qb = *(const float4*)&Qs[qi1][4 * d4];
      f32x2 kA = {k4.x, k4.y};
      f32x2 kB = {k4.z, k4.w};
      // (q - k) FIRST, then + eps: collision-safe (see header comment)
      f32x2 dA0 = ((f32x2){qa.x, qa.y} - kA) + eps2;
      f32x2 dB0 = ((f32x2){qa.z, qa.w} - kB) + eps2;
      f32x2 dA1 = ((f32x2){qb.x, qb.y} - kA) + eps2;
      f32x2 dB1 = ((f32x2){qb.z, qb.w} - kB) + eps2;
      f32x2 gA0 = cR2 * dA0, gB0 = cR2 * dB0;
      f32x2 gA1 = cR2 * dA1, gB1 = cR2 * dB1;
      f32x2 sA0, sB0, sA1, sB1;
      sA0.x = __builtin_amdgcn_sinf(gA0.x);
      sA0.y = __builtin_amdgcn_sinf(gA0.y);
      sB0.x = __builtin_amdgcn_sinf(gB0.x);
      sB0.y = __builtin_amdgcn_sinf(gB0.y);
      sA1.x = __builtin_amdgcn_sinf(gA1.x);
      sA1.y = __builtin_amdgcn_sinf(gA1.y);
      sB1.x = __builtin_amdgcn_sinf(gB1.x);
      sB1.y = __builtin_amdgcn_sinf(gB1.y);
      nmA0 *= sA0;
      nmB0 *= sB0;
      nmA1 *= sA1;
      nmB1 *= sB1;
      dnA0 *= dA0;
      dnB0 *= dB0;
      dnA1 *= dA1;
      dnB1 *= dB1;
    }
    {
      f32x2 n0 = nmA0 * nmB0, d0 = dnA0 * dnB0;
      f32x2 n1 = nmA1 * nmB1, d1 = dnA1 * dnB1;
      float sc0 = (n0.x * n0.y) / (d0.x * d0.y);
      float sc1 = (n1.x * n1.y) / (d1.x * d1.y);
      float t0 = sc0 * sc0, t1 = sc1 * sc1;
      float a40 = t0 * t0, a41 = t1 * t1;
      Sp[0] += a40;
      Sp[1] += a41;
      unsigned short h0 = f2bf(a40), h1 = f2bf(a41);
      Pah[qi0][lane] = h0;
      Pal[qi0][lane] = f2bf(a40 - bf2f(h0));
      Pah[qi1][lane] = h1;
      Pal[qi1][lane] = f2bf(a41 - bf2f(h1));
    }
    __syncthreads();  // B3: P tile complete

    // ---- AV phase: one 16x16x32 MFMA triple per wave
    {
      bf16x8 pah = *(const bf16x8*)&Pah[l16][kb];
      bf16x8 pal = *(const bf16x8*)&Pal[l16][kb];
      bf16x8 vh, vl;
#pragma unroll
      for (int j = 0; j < 8; j++) {
        float f = Vs[kb + j][nc * 16 + l16];
        unsigned short hb = f2bf(f);
        vh[j] = (short)hb;
        vl[j] = (short)f2bf(f - bf2f(hb));
      }
      oacc = __builtin_amdgcn_mfma_f32_16x16x32_bf16(pah, vh, oacc, 0, 0, 0);
      oacc = __builtin_amdgcn_mfma_f32_16x16x32_bf16(pah, vl, oacc, 0, 0, 0);
      oacc = __builtin_amdgcn_mfma_f32_16x16x32_bf16(pal, vh, oacc, 0, 0, 0);
    }
  }
#undef LOADT

  // ---- finalize: denominators, cross-wave pair-sum, normalize, store
#pragma unroll
  for (int q = 0; q < 2; q++) {
    float s = Sp[q];
#pragma unroll
    for (int off = 32; off > 0; off >>= 1) s += __shfl_xor(s, off, 64);
    if (lane == 0) Sden[qi0 + q] = s;
  }
  if (wv >= 4) Red[wv - 4][lane] = oacc;
  __syncthreads();
  if (wv < 4) {
    f32x4 part = Red[wv][lane];
#pragma unroll
    for (int r = 0; r < 4; r++) {
      int q = quad * 4 + r;
      float s = Sden[q];
      float o = (oacc[r] + part[r]) / (s + 1e-6f);
      int n = qc * 16 + q;
      size_t idx = (size_t)(b * NN + n) * CC + h * DH + nc * 16 + l16;
      unsigned short oh = f2bf(o);
      aoh[idx] = oh;
      aol[idx] = f2bf(o - bf2f(oh));
    }
  }
}

// ---------------------------------------------------------------------------
extern "C" void kernel_launch(void* const* d_in, const int* in_sizes, int n_in,
                              void* d_out, int out_size, void* d_ws,
                              size_t ws_size, hipStream_t stream) {
  const float* x = (const float*)d_in[0];       // (B,N,C)
  const float* w_qkv = (const float*)d_in[1];   // (3C, C)
  const float* w_proj = (const float*)d_in[2];  // (C, C)
  const float* b_proj = (const float*)d_in[3];  // (C,)
  const float* paramR = (const float*)d_in[4];  // (1,)
  float* outp = (float*)d_out;                  // (B,N,C)

  const int nX = BB * NN * CC;  // 524288
  const int nWq = 3 * CC * CC;  // 786432
  const int nWp = CC * CC;      // 262144

  // ws layout (all 16B-aligned)
  unsigned short* xh = (unsigned short*)d_ws;
  unsigned short* xl = xh + nX;
  unsigned short* wqh = xl + nX;
  unsigned short* wql = wqh + nWq;
  unsigned short* wph = wql + nWq;
  unsigned short* wpl = wph + nWp;
  unsigned short* aoh = wpl + nWp;
  unsigned short* aol = aoh + nX;
  float* qkv_ws = (float*)(aol + nX);  // 1024*1536 fp32

  // 1) hi/lo conversions (single fused launch: 512 + 768 + 256 blocks)
  cvt_hilo3<<<1536, 256, 0, stream>>>(x, xh, xl, w_qkv, wqh, wql, w_proj, wph,
                                      wpl);

  // 2) qkv = x @ w_qkv^T : M=1024, N=1536, K=512  (24x16 = 384 blocks)
  gemm_mfma<false><<<dim3(3 * CC / 64, BB * NN / 64), 256, 0, stream>>>(
      xh, xl, wqh, wql, nullptr, qkv_ws, BB * NN, 3 * CC, CC);

  // 3) fused fourier attention -> hi/lo bf16 (B*N, C)
  fourier_attn<<<dim3(NN / 16, HH, BB), 512, 0, stream>>>(qkv_ws, paramR, aoh,
                                                          aol);

  // 4) out = attn @ w_proj^T + b_proj : M=1024, N=512, K=512 (8x16 = 128 blk)
  gemm_mfma<true><<<dim3(CC / 64, BB * NN / 64), 256, 0, stream>>>(
      aoh, aol, wph, wpl, b_proj, outp, BB * NN, CC, CC);
}